// Round 1
// baseline (713.624 us; speedup 1.0000x reference)
//
#include <hip/hip_runtime.h>
#include <math.h>

#define MSTEP 200
#define NF 64
#define NA 64
#define NG 56            // padded row-groups of 4 -> 224 rows
#define MPADR 224

// float index of the 4-row group (f, g) in swizzled transposed LDS tile.
// 16B slots XOR-swizzled by f so both per-lane-row reads (fixed f, lanes=g)
// and transpose writes (fixed g, lanes=f) hit the minimal 8-phase pattern.
__device__ __forceinline__ int memT_off(int f, int g) {
    int slot = (g & ~7) | ((g ^ f) & 7);
    return f * (NG * 4) + slot * 4;
}

__device__ __forceinline__ float ftanh(float x) {
    float e = __expf(2.0f * x);
    return 1.0f - 2.0f / (e + 1.0f);
}

__launch_bounds__(256, 2)
__global__ void customAttention_48515950576474_kernel(
    const float* __restrict__ x, const float* __restrict__ mem,
    const float* __restrict__ Wq, const float* __restrict__ Wk,
    const float* __restrict__ bias, const float* __restrict__ Ws,
    float* __restrict__ out)
{
    __shared__ float memT[NF * NG * 4];      // 57344 B, mem[b] transposed [f][m]
    __shared__ float scores_part[4][MPADR];  // per-wave score partials
    __shared__ float weights[MPADR];
    __shared__ float x_lds[NF];
    __shared__ float ws_lds[NA];
    __shared__ float q_lds[NA];
    __shared__ float wmem_part[4][NF];
    __shared__ float redmax[4], redsum[4];

    const int t    = threadIdx.x;
    const int b    = blockIdx.x;
    const int f    = t & 63;
    const int tg   = t >> 6;       // wave id 0..3
    const int lane = t & 63;
    const int a0   = tg * 16;      // this wave's output-column block

    const float* memb = mem + (size_t)b * (MSTEP * NF);

    if (t < NF) {
        x_lds[t]  = x[(size_t)b * NF + t];
        ws_lds[t] = Ws[t];
    }

    // ---- Phase 1: stage mem[b] transposed+swizzled into LDS, zero pad rows
    #pragma unroll
    for (int p = 0; p < 14; ++p) {
        int g  = tg + 4 * p;
        int m0 = 4 * g;
        float4 v;
        v.x = (m0 + 0 < MSTEP) ? memb[(m0 + 0) * NF + f] : 0.0f;
        v.y = (m0 + 1 < MSTEP) ? memb[(m0 + 1) * NF + f] : 0.0f;
        v.z = (m0 + 2 < MSTEP) ? memb[(m0 + 2) * NF + f] : 0.0f;
        v.w = (m0 + 3 < MSTEP) ? memb[(m0 + 3) * NF + f] : 0.0f;
        *(float4*)&memT[memT_off(f, g)] = v;
    }
    __syncthreads();

    // ---- Phase 1.5: each wave computes its own q slice q[a0..a0+15]
    {
        int aj = lane & 15;
        int fh = lane >> 4;
        float qp = 0.0f;
        #pragma unroll
        for (int k = 0; k < 16; ++k) {
            int ff = fh * 16 + k;
            qp += x_lds[ff] * Wq[ff * NA + a0 + aj];
        }
        qp += __shfl_xor(qp, 16);
        qp += __shfl_xor(qp, 32);
        if (fh == 0) q_lds[a0 + aj] = qp + bias[a0 + aj];
    }

    // ---- Phase 2: key tile [4 rows x 16 cols] per lane, on the fly
    const int g2 = (lane < NG) ? lane : (NG - 1);  // clamp spare lanes (masked later)
    float acc[4][16];
    #pragma unroll
    for (int r = 0; r < 4; ++r)
        #pragma unroll
        for (int j = 0; j < 16; ++j) acc[r][j] = 0.0f;

    const int a0u = __builtin_amdgcn_readfirstlane(a0);  // force scalar Wk loads

    #pragma unroll 8
    for (int ff = 0; ff < NF; ++ff) {
        float4 mv = *(const float4*)&memT[memT_off(ff, g2)];
        float wkv[16];
        #pragma unroll
        for (int j = 0; j < 16; ++j) wkv[j] = Wk[ff * NA + a0u + j];
        #pragma unroll
        for (int r = 0; r < 4; ++r) {
            float m_r = (r == 0) ? mv.x : (r == 1) ? mv.y : (r == 2) ? mv.z : mv.w;
            #pragma unroll
            for (int j = 0; j < 16; ++j)
                acc[r][j] = fmaf(m_r, wkv[j], acc[r][j]);
        }
    }

    // ---- Phase 2 epilogue: tanh + Ws dot -> per-wave score partials
    {
        float qv[16], wsv[16];
        #pragma unroll
        for (int j = 0; j < 16; j += 4) {
            *(float4*)&qv[j]  = *(const float4*)&q_lds[a0 + j];
            *(float4*)&wsv[j] = *(const float4*)&ws_lds[a0 + j];
        }
        float sc[4];
        #pragma unroll
        for (int r = 0; r < 4; ++r) {
            float s = 0.0f;
            #pragma unroll
            for (int j = 0; j < 16; ++j)
                s += ftanh(qv[j] + acc[r][j]) * wsv[j];
            sc[r] = s;
        }
        if (lane < NG)
            *(float4*)&scores_part[tg][4 * lane] = make_float4(sc[0], sc[1], sc[2], sc[3]);
    }
    __syncthreads();

    // ---- Phase 3: softmax over m (thread t <-> row t)
    {
        float s = -INFINITY;
        if (t < MPADR) {
            s = scores_part[0][t] + scores_part[1][t] + scores_part[2][t] + scores_part[3][t];
            if (t >= MSTEP) s = -INFINITY;
        }
        float mx = s;
        #pragma unroll
        for (int d = 1; d < 64; d <<= 1) mx = fmaxf(mx, __shfl_xor(mx, d));
        if (lane == 0) redmax[tg] = mx;
        __syncthreads();
        mx = fmaxf(fmaxf(redmax[0], redmax[1]), fmaxf(redmax[2], redmax[3]));
        float e = (t < MSTEP) ? __expf(s - mx) : 0.0f;
        float sm = e;
        #pragma unroll
        for (int d = 1; d < 64; d <<= 1) sm += __shfl_xor(sm, d);
        if (lane == 0) redsum[tg] = sm;
        __syncthreads();
        float tot = redsum[0] + redsum[1] + redsum[2] + redsum[3];
        if (t < MPADR) weights[t] = e / tot;
    }
    __syncthreads();

    // ---- Phase 4: wmem[f] = sum_m w[m] * mem[m][f]
    {
        float part = 0.0f;
        #pragma unroll
        for (int k = 0; k < 14; ++k) {
            int g = tg * 14 + k;
            float4 mv = *(const float4*)&memT[memT_off(f, g)];
            float4 wv = *(const float4*)&weights[4 * g];
            part = fmaf(mv.x, wv.x, part);
            part = fmaf(mv.y, wv.y, part);
            part = fmaf(mv.z, wv.z, part);
            part = fmaf(mv.w, wv.w, part);
        }
        wmem_part[tg][f] = part;
    }
    __syncthreads();

    // ---- Phase 5: context[a] = sum_f wmem[f] * Wk[f][a], 4 waves x 16 cols
    {
        float wm = wmem_part[0][lane] + wmem_part[1][lane]
                 + wmem_part[2][lane] + wmem_part[3][lane];  // lane holds wmem[lane]
        int aj = lane & 15;
        int fh = lane >> 4;
        float ctx = 0.0f;
        #pragma unroll
        for (int k = 0; k < 16; ++k) {
            int ff = fh * 16 + k;
            float wmf = __shfl(wm, ff);
            ctx = fmaf(wmf, Wk[ff * NA + a0 + aj], ctx);
        }
        ctx += __shfl_xor(ctx, 16);
        ctx += __shfl_xor(ctx, 32);
        if (fh == 0) out[(size_t)b * NA + a0 + aj] = ctx;
    }
}

extern "C" void kernel_launch(void* const* d_in, const int* in_sizes, int n_in,
                              void* d_out, int out_size, void* d_ws, size_t ws_size,
                              hipStream_t stream) {
    const float* x    = (const float*)d_in[0];
    const float* mem  = (const float*)d_in[1];
    const float* Wq   = (const float*)d_in[2];
    const float* Wk   = (const float*)d_in[3];
    const float* bias = (const float*)d_in[4];
    const float* Ws   = (const float*)d_in[5];
    float* out = (float*)d_out;
    const int B = in_sizes[0] / NF;  // 8192
    customAttention_48515950576474_kernel<<<B, 256, 0, stream>>>(x, mem, Wq, Wk, bias, Ws, out);
}

// Round 6
// 655.461 us; speedup vs baseline: 1.0887x; 1.0887x over previous
//
#include <hip/hip_runtime.h>
#include <math.h>

#define MSTEP 200
#define NF 64
#define NA 64
#define MROWS 208   // 13 tiles of 16
#define NMT 13

typedef __bf16 bf16x4 __attribute__((ext_vector_type(4)));
typedef __bf16 bf16x8 __attribute__((ext_vector_type(8)));
typedef float  floatx4 __attribute__((ext_vector_type(4)));

// LDS layout for bf16 tiles: row-major [row][64], 8 slots of 8 elements (16B)
// per row, slot index XOR-swizzled by (row&7) -> conflict-free b128 frag reads
// (16 lanes, stride-128B rows) AND conflict-free staging writes.

__launch_bounds__(256, 2)
__global__ void customAttention_48515950576474_kernel(
    const float* __restrict__ x, const float* __restrict__ mem,
    const float* __restrict__ Wq, const float* __restrict__ Wk,
    const float* __restrict__ bias, const float* __restrict__ Ws,
    float* __restrict__ out)
{
    __shared__ __align__(16) __bf16 mh[MROWS * NF];  // mem hi  (26.6 KB)
    __shared__ __align__(16) __bf16 ml[MROWS * NF];  // mem lo  (26.6 KB)
    __shared__ __align__(16) __bf16 wh[NA * NF];     // Wk^T hi (8 KB)
    __shared__ __align__(16) __bf16 wl[NA * NF];     // Wk^T lo (8 KB)
    __shared__ float q_lds[NA];
    __shared__ float scores[MROWS];
    __shared__ float weights[MROWS];
    __shared__ float ctxp[4][NA];
    __shared__ float redmax[4], redsum[4];

    const int t    = threadIdx.x;
    const int b    = blockIdx.x;
    const int w    = t >> 6;       // wave 0..3
    const int lane = t & 63;

    // ---- stage mem[b] -> bf16 hi/lo, swizzled [m][k]. 3200 float4, coalesced.
    const float4* memb4 = (const float4*)(mem + (size_t)b * (MSTEP * NF));
    for (int it = 0; it < 13; ++it) {
        int fi = t + (it << 8);
        if (fi < MSTEP * 16) {
            float4 v = memb4[fi];
            int m = fi >> 4, qq = fi & 15;                 // 16 float4 per row
            int eo = m * 64 + (((qq >> 1) ^ (m & 7)) << 3) + ((qq & 1) << 2);
            float vv[4] = {v.x, v.y, v.z, v.w};
            bf16x4 h, l;
            #pragma unroll
            for (int j = 0; j < 4; ++j) {
                __bf16 hb = (__bf16)vv[j];
                h[j] = hb;
                l[j] = (__bf16)(vv[j] - (float)hb);
            }
            *(bf16x4*)&mh[eo] = h;
            *(bf16x4*)&ml[eo] = l;
        }
    }
    // zero-fill pad rows 200..207 (avoid stale-LDS NaN reaching MFMA A-frags)
    if (t < 64) {
        int m = MSTEP + (t >> 3), c = t & 7;
        int eo = m * 64 + ((c ^ (m & 7)) << 3);
        *(float4*)&mh[eo] = make_float4(0.f, 0.f, 0.f, 0.f);
        *(float4*)&ml[eo] = make_float4(0.f, 0.f, 0.f, 0.f);
    }

    // ---- stage Wk^T -> bf16 hi/lo (transpose, 4096 scalar elems)
    for (int i = 0; i < 16; ++i) {
        int idx = t + (i << 8);
        int kk = idx >> 6, a = idx & 63;
        float v = Wk[idx];                                  // coalesced dword
        __bf16 hb = (__bf16)v;
        int eo = a * 64 + ((((kk >> 3) ^ (a & 7))) << 3) + (kk & 7);
        wh[eo] = hb;
        wl[eo] = (__bf16)(v - (float)hb);
    }

    // ---- q = x@Wq + bias, wave w computes cols [16w, 16w+16)
    {
        float xv = x[(size_t)b * NF + lane];
        int aj = lane & 15, fh = lane >> 4;
        int a0 = w << 4;
        float qp = 0.f;
        #pragma unroll
        for (int kx = 0; kx < 16; ++kx) {
            int ff = fh * 16 + kx;
            qp = fmaf(__shfl(xv, ff), Wq[ff * NA + a0 + aj], qp);
        }
        qp += __shfl_xor(qp, 16);
        qp += __shfl_xor(qp, 32);
        if (fh == 0) q_lds[a0 + aj] = qp + bias[a0 + aj];
    }
    __syncthreads();

    // ---- key via 3-MFMA split-bf16; keep key in registers (kreg)
    bf16x8 bh[4][2], bl[4][2];          // B-frags (Wk^T), hoisted
    {
        int a = lane & 15, ko = lane >> 4;
        #pragma unroll
        for (int at = 0; at < 4; ++at) {
            int row = at * 16 + a;
            #pragma unroll
            for (int kc = 0; kc < 2; ++kc) {
                int eo = row * 64 + (((kc * 4 + ko) ^ (row & 7)) << 3);
                bh[at][kc] = *(const bf16x8*)&wh[eo];
                bl[at][kc] = *(const bf16x8*)&wl[eo];
            }
        }
    }

    floatx4 kreg[4][4];                 // [i][atile]: key values, near-fp32
    #pragma unroll
    for (int i = 0; i < 4; ++i)
        #pragma unroll
        for (int at = 0; at < 4; ++at)
            kreg[i][at] = (floatx4){0.f, 0.f, 0.f, 0.f};

    float qv[4], wsv[4];
    #pragma unroll
    for (int at = 0; at < 4; ++at) {
        int a = at * 16 + (lane & 15);
        qv[at]  = q_lds[a];
        wsv[at] = Ws[a];
    }

    #pragma unroll
    for (int i = 0; i < 4; ++i) {
        int mt = w + 4 * i;             // wave w owns mtiles w, w+4, w+8 (+12 for w=0)
        if (mt < NMT) {
            int m = mt * 16 + (lane & 15);
            int ko = lane >> 4;
            bf16x8 ah[2], al[2];
            #pragma unroll
            for (int kc = 0; kc < 2; ++kc) {
                int eo = m * 64 + (((kc * 4 + ko) ^ (m & 7)) << 3);
                ah[kc] = *(const bf16x8*)&mh[eo];
                al[kc] = *(const bf16x8*)&ml[eo];
            }
            #pragma unroll
            for (int at = 0; at < 4; ++at) {
                floatx4 acc = kreg[i][at];
                #pragma unroll
                for (int kc = 0; kc < 2; ++kc) {
                    acc = __builtin_amdgcn_mfma_f32_16x16x32_bf16(ah[kc], bh[at][kc], acc, 0, 0, 0);
                    acc = __builtin_amdgcn_mfma_f32_16x16x32_bf16(ah[kc], bl[at][kc], acc, 0, 0, 0);
                    acc = __builtin_amdgcn_mfma_f32_16x16x32_bf16(al[kc], bh[at][kc], acc, 0, 0, 0);
                }
                kreg[i][at] = acc;
            }
            // epilogue: s[m] = sum_a tanh(key + q[a]) * ws[a]
            float s[4] = {0.f, 0.f, 0.f, 0.f};
            #pragma unroll
            for (int at = 0; at < 4; ++at) {
                #pragma unroll
                for (int r = 0; r < 4; ++r) {
                    float e  = __expf(2.f * (kreg[i][at][r] + qv[at]));
                    float th = 1.f - 2.f / (e + 1.f);
                    s[r] = fmaf(th, wsv[at], s[r]);
                }
            }
            #pragma unroll
            for (int r = 0; r < 4; ++r) {
                s[r] += __shfl_xor(s[r], 1);
                s[r] += __shfl_xor(s[r], 2);
                s[r] += __shfl_xor(s[r], 4);
                s[r] += __shfl_xor(s[r], 8);
            }
            if ((lane & 15) == 0) {
                int mrow = mt * 16 + (lane >> 4) * 4;
                scores[mrow + 0] = s[0];
                scores[mrow + 1] = s[1];
                scores[mrow + 2] = s[2];
                scores[mrow + 3] = s[3];
            }
        }
    }
    __syncthreads();

    // ---- softmax over m (200 valid rows)
    {
        float sv = (t < MSTEP) ? scores[t] : -INFINITY;
        float mx = sv;
        #pragma unroll
        for (int d = 1; d < 64; d <<= 1) mx = fmaxf(mx, __shfl_xor(mx, d));
        if (lane == 0) redmax[w] = mx;
        __syncthreads();
        mx = fmaxf(fmaxf(redmax[0], redmax[1]), fmaxf(redmax[2], redmax[3]));
        float e = (t < MSTEP) ? __expf(sv - mx) : 0.f;
        float sm = e;
        #pragma unroll
        for (int d = 1; d < 64; d <<= 1) sm += __shfl_xor(sm, d);
        if (lane == 0) redsum[w] = sm;
        __syncthreads();
        float tot = redsum[0] + redsum[1] + redsum[2] + redsum[3];
        if (t < MROWS) weights[t] = e / tot;     // rows 200..207 get 0
    }
    __syncthreads();

    // ---- context[a] = sum_m w[m] * key[m][a], straight from kreg
    {
        float c[4] = {0.f, 0.f, 0.f, 0.f};
        #pragma unroll
        for (int i = 0; i < 4; ++i) {
            int mt = w + 4 * i;
            if (mt < NMT) {
                int mrow = mt * 16 + (lane >> 4) * 4;
                #pragma unroll
                for (int r = 0; r < 4; ++r) {
                    float wv = weights[mrow + r];
                    #pragma unroll
                    for (int at = 0; at < 4; ++at)
                        c[at] = fmaf(wv, kreg[i][at][r], c[at]);
                }
            }
        }
        #pragma unroll
        for (int at = 0; at < 4; ++at) {
            c[at] += __shfl_xor(c[at], 16);
            c[at] += __shfl_xor(c[at], 32);
        }
        if (lane < 16) {
            #pragma unroll
            for (int at = 0; at < 4; ++at)
                ctxp[w][at * 16 + lane] = c[at];
        }
    }
    __syncthreads();

    if (t < NA)
        out[(size_t)b * NA + t] = ctxp[0][t] + ctxp[1][t] + ctxp[2][t] + ctxp[3][t];
}

extern "C" void kernel_launch(void* const* d_in, const int* in_sizes, int n_in,
                              void* d_out, int out_size, void* d_ws, size_t ws_size,
                              hipStream_t stream) {
    const float* x    = (const float*)d_in[0];
    const float* mem  = (const float*)d_in[1];
    const float* Wq   = (const float*)d_in[2];
    const float* Wk   = (const float*)d_in[3];
    const float* bias = (const float*)d_in[4];
    const float* Ws   = (const float*)d_in[5];
    float* out = (float*)d_out;
    const int B = in_sizes[0] / NF;  // 8192
    customAttention_48515950576474_kernel<<<B, 256, 0, stream>>>(x, mem, Wq, Wk, bias, Ws, out);
}

// Round 8
// 589.305 us; speedup vs baseline: 1.2110x; 1.1123x over previous
//
#include <hip/hip_runtime.h>
#include <math.h>

#define MSTEP 200
#define NF 64
#define NA 64
#define NMT 13   // 13 m-tiles of 16 -> 208 rows (200 valid)

typedef __bf16 bf16x8 __attribute__((ext_vector_type(8)));
typedef float  floatx4 __attribute__((ext_vector_type(4)));

// Wk^T LDS tile: row-major [a][64], 8 slots of 8 bf16 (16B) per row,
// slot XOR-swizzled by (a&7) -> conflict-free b128 frag reads and writes.

__launch_bounds__(256, 3)
__global__ void customAttention_48515950576474_kernel(
    const float* __restrict__ x, const float* __restrict__ mem,
    const float* __restrict__ Wq, const float* __restrict__ Wk,
    const float* __restrict__ bias, const float* __restrict__ Ws,
    float* __restrict__ out)
{
    __shared__ __align__(16) __bf16 wh[NA * NF];   // Wk^T hi (8 KB)
    __shared__ __align__(16) __bf16 wl[NA * NF];   // Wk^T lo (8 KB)
    __shared__ float q_lds[NA];
    __shared__ float scores[NMT * 16];             // 208
    __shared__ float ctxp[4][NA];

    const int t    = threadIdx.x;
    const int b    = blockIdx.x;
    const int w    = t >> 6;       // wave 0..3
    const int lane = t & 63;

    const float* memb = mem + (size_t)b * (MSTEP * NF);

    // ---- stage Wk^T -> bf16 hi/lo in LDS (shared by all 4 waves)
    for (int i = 0; i < 16; ++i) {
        int idx = t + (i << 8);
        int kk = idx >> 6, a = idx & 63;
        float v = Wk[idx];                         // coalesced dword
        __bf16 hb = (__bf16)v;
        int eo = a * 64 + (((kk >> 3) ^ (a & 7)) << 3) + (kk & 7);
        wh[eo] = hb;
        wl[eo] = (__bf16)(v - (float)hb);
    }

    // ---- q = x@Wq + bias, wave w computes cols [16w, 16w+16)
    {
        float xv = x[(size_t)b * NF + lane];
        int aj = lane & 15, fh = lane >> 4;
        int a0 = w << 4;
        float qp = 0.f;
        #pragma unroll
        for (int kx = 0; kx < 16; ++kx) {
            int ff = fh * 16 + kx;
            qp = fmaf(__shfl(xv, ff), Wq[ff * NA + a0 + aj], qp);
        }
        qp += __shfl_xor(qp, 16);
        qp += __shfl_xor(qp, 32);
        if (fh == 0) q_lds[a0 + aj] = qp + bias[a0 + aj];
    }
    __syncthreads();   // barrier 1 (Wk^T + q visible)

    // ---- hoist B-frags (Wk^T) from LDS
    bf16x8 bh[4][2], bl[4][2];
    {
        int a = lane & 15, ko = lane >> 4;
        #pragma unroll
        for (int at = 0; at < 4; ++at) {
            int row = at * 16 + a;
            #pragma unroll
            for (int kc = 0; kc < 2; ++kc) {
                int eo = row * 64 + ((((kc * 4 + ko)) ^ (row & 7)) << 3);
                bh[at][kc] = *(const bf16x8*)&wh[eo];
                bl[at][kc] = *(const bf16x8*)&wl[eo];
            }
        }
    }

    float qv[4], wsv[4];
    #pragma unroll
    for (int at = 0; at < 4; ++at) {
        int a = at * 16 + (lane & 15);
        qv[at]  = q_lds[a];
        wsv[at] = Ws[a];
    }

    floatx4 kreg[4][4];                 // [i][atile]: key values, near-fp32
    #pragma unroll
    for (int i = 0; i < 4; ++i)
        #pragma unroll
        for (int at = 0; at < 4; ++at)
            kreg[i][at] = (floatx4){0.f, 0.f, 0.f, 0.f};

    // ---- key via 3-MFMA split-bf16; A-frags loaded DIRECT global->reg
    #pragma unroll
    for (int i = 0; i < 4; ++i) {
        int mt = w + 4 * i;             // wave w owns mtiles w, w+4, w+8 (+12 for w=0)
        if (mt < NMT) {
            int m  = mt * 16 + (lane & 15);
            int ko = lane >> 4;
            bool valid = (m < MSTEP);   // rows 200..207 -> zero A (and no OOB at b=8191)
            bf16x8 ah[2], al[2];
            #pragma unroll
            for (int kc = 0; kc < 2; ++kc) {
                const float* ap = memb + m * 64 + kc * 32 + ko * 8;
                float4 p0 = valid ? *(const float4*)ap       : make_float4(0.f, 0.f, 0.f, 0.f);
                float4 p1 = valid ? *(const float4*)(ap + 4) : make_float4(0.f, 0.f, 0.f, 0.f);
                float vv[8] = {p0.x, p0.y, p0.z, p0.w, p1.x, p1.y, p1.z, p1.w};
                bf16x8 h, l;
                #pragma unroll
                for (int j = 0; j < 8; ++j) {
                    __bf16 hb = (__bf16)vv[j];
                    h[j] = hb;
                    l[j] = (__bf16)(vv[j] - (float)hb);
                }
                ah[kc] = h;
                al[kc] = l;
            }
            #pragma unroll
            for (int at = 0; at < 4; ++at) {
                floatx4 acc = kreg[i][at];
                #pragma unroll
                for (int kc = 0; kc < 2; ++kc) {
                    acc = __builtin_amdgcn_mfma_f32_16x16x32_bf16(ah[kc], bh[at][kc], acc, 0, 0, 0);
                    acc = __builtin_amdgcn_mfma_f32_16x16x32_bf16(ah[kc], bl[at][kc], acc, 0, 0, 0);
                    acc = __builtin_amdgcn_mfma_f32_16x16x32_bf16(al[kc], bh[at][kc], acc, 0, 0, 0);
                }
                kreg[i][at] = acc;
            }
            // epilogue: s[m] = sum_a tanh(key + q[a]) * ws[a]
            float s[4] = {0.f, 0.f, 0.f, 0.f};
            #pragma unroll
            for (int at = 0; at < 4; ++at) {
                #pragma unroll
                for (int r = 0; r < 4; ++r) {
                    float e  = __expf(2.f * (kreg[i][at][r] + qv[at]));
                    float th = 1.f - 2.f / (e + 1.f);
                    s[r] = fmaf(th, wsv[at], s[r]);
                }
            }
            #pragma unroll
            for (int r = 0; r < 4; ++r) {
                s[r] += __shfl_xor(s[r], 1);
                s[r] += __shfl_xor(s[r], 2);
                s[r] += __shfl_xor(s[r], 4);
                s[r] += __shfl_xor(s[r], 8);
            }
            if ((lane & 15) == 0) {
                int mrow = mt * 16 + (lane >> 4) * 4;   // rows 200..207 stored but never read
                scores[mrow + 0] = s[0];
                scores[mrow + 1] = s[1];
                scores[mrow + 2] = s[2];
                scores[mrow + 3] = s[3];
            }
        }
    }
    __syncthreads();   // barrier 2 (scores visible)

    // ---- softmax stats, computed redundantly per wave (no extra barriers)
    float mx, inv;
    {
        float s0 = scores[lane];
        float s1 = scores[lane + 64];
        float s2 = scores[lane + 128];                     // <= 191, always valid
        float s3 = (lane < 8) ? scores[lane + 192] : -INFINITY;   // 192..199 only
        mx = fmaxf(fmaxf(s0, s1), fmaxf(s2, s3));
        #pragma unroll
        for (int d = 1; d < 64; d <<= 1) mx = fmaxf(mx, __shfl_xor(mx, d));
        float e = __expf(s0 - mx) + __expf(s1 - mx) + __expf(s2 - mx)
                + ((lane < 8) ? __expf(s3 - mx) : 0.f);
        #pragma unroll
        for (int d = 1; d < 64; d <<= 1) e += __shfl_xor(e, d);
        inv = 1.0f / e;
    }

    // ---- context[a] = sum_m softmax(scores)[m] * key[m][a], from kreg
    {
        float c[4] = {0.f, 0.f, 0.f, 0.f};
        #pragma unroll
        for (int i = 0; i < 4; ++i) {
            int mt = w + 4 * i;
            if (mt < NMT) {
                int mrow = mt * 16 + (lane >> 4) * 4;
                #pragma unroll
                for (int r = 0; r < 4; ++r) {
                    float wv = (mrow + r < MSTEP)
                             ? __expf(scores[mrow + r] - mx) * inv : 0.f;
                    #pragma unroll
                    for (int at = 0; at < 4; ++at)
                        c[at] = fmaf(wv, kreg[i][at][r], c[at]);
                }
            }
        }
        #pragma unroll
        for (int at = 0; at < 4; ++at) {
            c[at] += __shfl_xor(c[at], 16);
            c[at] += __shfl_xor(c[at], 32);
        }
        if (lane < 16) {
            #pragma unroll
            for (int at = 0; at < 4; ++at)
                ctxp[w][at * 16 + lane] = c[at];
        }
    }
    __syncthreads();   // barrier 3 (ctxp visible)

    if (t < NA)
        out[(size_t)b * NA + t] = ctxp[0][t] + ctxp[1][t] + ctxp[2][t] + ctxp[3][t];
}

extern "C" void kernel_launch(void* const* d_in, const int* in_sizes, int n_in,
                              void* d_out, int out_size, void* d_ws, size_t ws_size,
                              hipStream_t stream) {
    const float* x    = (const float*)d_in[0];
    const float* mem  = (const float*)d_in[1];
    const float* Wq   = (const float*)d_in[2];
    const float* Wk   = (const float*)d_in[3];
    const float* bias = (const float*)d_in[4];
    const float* Ws   = (const float*)d_in[5];
    float* out = (float*)d_out;
    const int B = in_sizes[0] / NF;  // 8192
    customAttention_48515950576474_kernel<<<B, 256, 0, stream>>>(x, mem, Wq, Wk, bias, Ws, out);
}

// Round 10
// 577.540 us; speedup vs baseline: 1.2356x; 1.0204x over previous
//
#include <hip/hip_runtime.h>
#include <math.h>

#define MSTEP 200
#define NF 64
#define NA 64
#define NMT 13   // 13 m-tiles of 16 -> 208 rows (200 valid)

typedef __bf16 bf16x8 __attribute__((ext_vector_type(8)));
typedef float  floatx4 __attribute__((ext_vector_type(4)));

// Wk^T LDS tile: row-major [a][64], 8 slots of 8 bf16 (16B) per row,
// slot XOR-swizzled by (a&7) -> conflict-free b128 reads and writes.

__launch_bounds__(256, 3)
__global__ void customAttention_48515950576474_kernel(
    const float* __restrict__ x, const float* __restrict__ mem,
    const float* __restrict__ Wq, const float* __restrict__ Wk,
    const float* __restrict__ bias, const float* __restrict__ Ws,
    float* __restrict__ out)
{
    __shared__ __align__(16) __bf16 wh[NA * NF];   // Wk^T hi (8 KB)
    __shared__ __align__(16) __bf16 wl[NA * NF];   // Wk^T lo (8 KB)
    __shared__ float q_lds[NA];
    __shared__ float scores[NMT * 16];             // 208
    __shared__ float ctxp[4][NA];

    const int t    = threadIdx.x;
    const int b    = blockIdx.x;
    const int w    = t >> 6;       // wave 0..3
    const int lane = t & 63;

    const float* memb = mem + (size_t)b * (MSTEP * NF);

    // ---- 0. Prefetch ALL owned A-tiles first: 16 dwordx4 loads in flight,
    //         overlapping each other AND the Wk/q staging below.
    float4 abuf[4][4];
    #pragma unroll
    for (int i = 0; i < 4; ++i) {
        int mt = w + 4 * i;
        int m  = mt * 16 + (lane & 15);
        bool valid = (mt < NMT) && (m < MSTEP);
        int mc = valid ? m : 0;                    // clamp: loads always in-bounds
        const float* ap = memb + mc * 64 + (lane >> 4) * 8;
        #pragma unroll
        for (int kc = 0; kc < 2; ++kc)
            #pragma unroll
            for (int h = 0; h < 2; ++h)
                abuf[i][kc * 2 + h] = *(const float4*)(ap + kc * 32 + h * 4);
        if (!valid) {
            #pragma unroll
            for (int p = 0; p < 4; ++p)
                abuf[i][p] = make_float4(0.f, 0.f, 0.f, 0.f);
        }
    }

    // ---- 1. stage Wk^T -> bf16 hi/lo in LDS (shared by all 4 waves)
    for (int i = 0; i < 16; ++i) {
        int idx = t + (i << 8);
        int kk = idx >> 6, a = idx & 63;
        float v = Wk[idx];                         // coalesced dword
        __bf16 hb = (__bf16)v;
        int eo = a * 64 + (((kk >> 3) ^ (a & 7)) << 3) + (kk & 7);
        wh[eo] = hb;
        wl[eo] = (__bf16)(v - (float)hb);
    }

    // ---- 2. q = x@Wq + bias, wave w computes cols [16w, 16w+16)
    {
        float xv = x[(size_t)b * NF + lane];
        int aj = lane & 15, fh = lane >> 4;
        int a0 = w << 4;
        float qp = 0.f;
        #pragma unroll
        for (int kx = 0; kx < 16; ++kx) {
            int ff = fh * 16 + kx;
            qp = fmaf(__shfl(xv, ff), Wq[ff * NA + a0 + aj], qp);
        }
        qp += __shfl_xor(qp, 16);
        qp += __shfl_xor(qp, 32);
        if (fh == 0) q_lds[a0 + aj] = qp + bias[a0 + aj];
    }
    __syncthreads();   // barrier 1 (Wk^T + q visible; all A loads also drained)

    float qv[4], wsv[4];
    #pragma unroll
    for (int at = 0; at < 4; ++at) {
        int a = at * 16 + (lane & 15);
        qv[at]  = q_lds[a];
        wsv[at] = Ws[a];
    }

    floatx4 kreg[4][4];                 // [i][atile]: key values, near-fp32
    #pragma unroll
    for (int i = 0; i < 4; ++i)
        #pragma unroll
        for (int at = 0; at < 4; ++at)
            kreg[i][at] = (floatx4){0.f, 0.f, 0.f, 0.f};

    // ---- 3. key via 3-MFMA split-bf16; A from abuf, B re-read from LDS
    #pragma unroll
    for (int i = 0; i < 4; ++i) {
        int mt = w + 4 * i;
        if (mt < NMT) {
            int a  = lane & 15;
            int ko = lane >> 4;
            // convert this tile's A to bf16 hi/lo (data already resident)
            bf16x8 ah[2], al[2];
            #pragma unroll
            for (int kc = 0; kc < 2; ++kc) {
                float4 p0 = abuf[i][kc * 2 + 0];
                float4 p1 = abuf[i][kc * 2 + 1];
                float vv[8] = {p0.x, p0.y, p0.z, p0.w, p1.x, p1.y, p1.z, p1.w};
                bf16x8 h, l;
                #pragma unroll
                for (int j = 0; j < 8; ++j) {
                    __bf16 hb = (__bf16)vv[j];
                    h[j] = hb;
                    l[j] = (__bf16)(vv[j] - (float)hb);
                }
                ah[kc] = h;
                al[kc] = l;
            }
            #pragma unroll
            for (int at = 0; at < 4; ++at) {
                int row = at * 16 + a;
                floatx4 acc = kreg[i][at];
                #pragma unroll
                for (int kc = 0; kc < 2; ++kc) {
                    int eo = row * 64 + (((kc * 4 + ko) ^ (row & 7)) << 3);
                    bf16x8 bhx = *(const bf16x8*)&wh[eo];
                    bf16x8 blx = *(const bf16x8*)&wl[eo];
                    acc = __builtin_amdgcn_mfma_f32_16x16x32_bf16(ah[kc], bhx, acc, 0, 0, 0);
                    acc = __builtin_amdgcn_mfma_f32_16x16x32_bf16(ah[kc], blx, acc, 0, 0, 0);
                    acc = __builtin_amdgcn_mfma_f32_16x16x32_bf16(al[kc], bhx, acc, 0, 0, 0);
                }
                kreg[i][at] = acc;
            }
            // epilogue: s[m] = sum_a tanh(key + q[a]) * ws[a]
            float s[4] = {0.f, 0.f, 0.f, 0.f};
            #pragma unroll
            for (int at = 0; at < 4; ++at) {
                #pragma unroll
                for (int r = 0; r < 4; ++r) {
                    float e  = __expf(2.f * (kreg[i][at][r] + qv[at]));
                    float th = 1.f - 2.f / (e + 1.f);
                    s[r] = fmaf(th, wsv[at], s[r]);
                }
            }
            #pragma unroll
            for (int r = 0; r < 4; ++r) {
                s[r] += __shfl_xor(s[r], 1);
                s[r] += __shfl_xor(s[r], 2);
                s[r] += __shfl_xor(s[r], 4);
                s[r] += __shfl_xor(s[r], 8);
            }
            if ((lane & 15) == 0) {
                int mrow = mt * 16 + (lane >> 4) * 4;   // rows 200..207 stored, never read
                scores[mrow + 0] = s[0];
                scores[mrow + 1] = s[1];
                scores[mrow + 2] = s[2];
                scores[mrow + 3] = s[3];
            }
        }
    }
    __syncthreads();   // barrier 2 (scores visible)

    // ---- 4. softmax stats, computed redundantly per wave (no extra barriers)
    float mx, inv;
    {
        float s0 = scores[lane];
        float s1 = scores[lane + 64];
        float s2 = scores[lane + 128];                     // <= 191, always valid
        float s3 = (lane < 8) ? scores[lane + 192] : -INFINITY;   // 192..199 only
        mx = fmaxf(fmaxf(s0, s1), fmaxf(s2, s3));
        #pragma unroll
        for (int d = 1; d < 64; d <<= 1) mx = fmaxf(mx, __shfl_xor(mx, d));
        float e = __expf(s0 - mx) + __expf(s1 - mx) + __expf(s2 - mx)
                + ((lane < 8) ? __expf(s3 - mx) : 0.f);
        #pragma unroll
        for (int d = 1; d < 64; d <<= 1) e += __shfl_xor(e, d);
        inv = 1.0f / e;
    }

    // ---- 5. context[a] = sum_m softmax(scores)[m] * key[m][a], from kreg
    {
        float c[4] = {0.f, 0.f, 0.f, 0.f};
        #pragma unroll
        for (int i = 0; i < 4; ++i) {
            int mt = w + 4 * i;
            if (mt < NMT) {
                int mrow = mt * 16 + (lane >> 4) * 4;
                #pragma unroll
                for (int r = 0; r < 4; ++r) {
                    float wv = (mrow + r < MSTEP)
                             ? __expf(scores[mrow + r] - mx) * inv : 0.f;
                    #pragma unroll
                    for (int at = 0; at < 4; ++at)
                        c[at] = fmaf(wv, kreg[i][at][r], c[at]);
                }
            }
        }
        #pragma unroll
        for (int at = 0; at < 4; ++at) {
            c[at] += __shfl_xor(c[at], 16);
            c[at] += __shfl_xor(c[at], 32);
        }
        if (lane < 16) {
            #pragma unroll
            for (int at = 0; at < 4; ++at)
                ctxp[w][at * 16 + lane] = c[at];
        }
    }
    __syncthreads();   // barrier 3 (ctxp visible)

    if (t < NA)
        out[(size_t)b * NA + t] = ctxp[0][t] + ctxp[1][t] + ctxp[2][t] + ctxp[3][t];
}

extern "C" void kernel_launch(void* const* d_in, const int* in_sizes, int n_in,
                              void* d_out, int out_size, void* d_ws, size_t ws_size,
                              hipStream_t stream) {
    const float* x    = (const float*)d_in[0];
    const float* mem  = (const float*)d_in[1];
    const float* Wq   = (const float*)d_in[2];
    const float* Wk   = (const float*)d_in[3];
    const float* bias = (const float*)d_in[4];
    const float* Ws   = (const float*)d_in[5];
    float* out = (float*)d_out;
    const int B = in_sizes[0] / NF;  // 8192
    customAttention_48515950576474_kernel<<<B, 256, 0, stream>>>(x, mem, Wq, Wk, bias, Ws, out);
}